// Round 4
// baseline (246.935 us; speedup 1.0000x reference)
//
#include <hip/hip_runtime.h>

#define B_DIM 4096
#define H_DIM 1024
#define K_DIM 2048   // IN + H
#define NTILE (K_DIM / 64)

typedef unsigned short u16;
typedef unsigned int u32;
typedef __attribute__((ext_vector_type(8))) short short8;
typedef __attribute__((ext_vector_type(4))) short s16x4;
typedef __attribute__((ext_vector_type(4))) float f32x4;

typedef const __attribute__((address_space(1))) void* gas_ptr;
typedef __attribute__((address_space(3))) void* las_ptr;

#define WT_ELEMS (4 * H_DIM * K_DIM)       // 8.39M u16
#define WS_NEEDED ((size_t)WT_ELEMS * 2)   // 16.78 MB (Wt only; A no longer materialized)

__device__ __forceinline__ void gl_lds16(const u16* g, u16* l) {
    __builtin_amdgcn_global_load_lds((gas_ptr)g, (las_ptr)l, 16, 0, 0);
}
__device__ __forceinline__ float bf2f(u16 v) {
    return __builtin_bit_cast(float, (u32)((u32)v << 16));
}
__device__ __forceinline__ u16 f2bf(float f) {
    u32 u = __builtin_bit_cast(u32, f);
    return (u16)((u + 0x7fffu + ((u >> 16) & 1u)) >> 16);
}
__device__ __forceinline__ s16x4 cvt4(float4 v) {
    s16x4 r;
    r[0] = (short)f2bf(v.x); r[1] = (short)f2bf(v.y);
    r[2] = (short)f2bf(v.z); r[3] = (short)f2bf(v.w);
    return r;
}
__device__ __forceinline__ float sigm(float x) { return 1.0f / (1.0f + __expf(-x)); }
__device__ __forceinline__ float tanh_f(float x) { return 1.0f - 2.0f / (__expf(2.0f * x) + 1.0f); }

// ---------- prep_W: 64x64 f32 [k][n] -> bf16 [n][k] via register 8x8 transpose (r2-verified) ----------
__global__ __launch_bounds__(256) void prep_W(const float* __restrict__ Wf, const float* __restrict__ Wi,
                                              const float* __restrict__ Wg, const float* __restrict__ Wo,
                                              u16* __restrict__ Wt) {
    const int id = blockIdx.x * 4 + ((int)threadIdx.x >> 6);   // one 64x64 tile per wave
    const int l = threadIdx.x & 63;
    const int k0 = (id & 31) * 64, n0 = ((id >> 5) & 15) * 64, g = id >> 9;
    const float* W = (g == 0) ? Wf : (g == 1) ? Wi : (g == 2) ? Wg : Wo;
    const int no = (l & 7) * 8;
    const int ko = (l >> 3) * 8;
    float f[8][8];
#pragma unroll
    for (int j = 0; j < 8; ++j) {
        const float4* s = (const float4*)(W + (size_t)(k0 + ko + j) * H_DIM + n0 + no);
        float4 a = s[0], b = s[1];
        f[j][0] = a.x; f[j][1] = a.y; f[j][2] = a.z; f[j][3] = a.w;
        f[j][4] = b.x; f[j][5] = b.y; f[j][6] = b.z; f[j][7] = b.w;
    }
    u16* dst0 = Wt + (size_t)g * ((size_t)H_DIM * K_DIM) + (size_t)(n0 + no) * K_DIM + k0 + ko;
#pragma unroll
    for (int w2 = 0; w2 < 8; ++w2) {
        short8 q;
#pragma unroll
        for (int j = 0; j < 8; ++j) q[j] = (short)f2bf(f[j][w2]);
        *(short8*)(dst0 + (size_t)w2 * K_DIM) = q;
    }
}

// ---------- fused GEMM + LSTM, A-prep FUSED (reg-staged f32->bf16), B via gl_lds ----------
// Block: 256 m x (4 gates x 64 cols), 512 thr = 8 waves. BK=64, 128 KiB double-buffered LDS.
// Per K-tile, 4 phases. A(kt+1): 8x global_load_dwordx4 f32 from x/h (4 issued in q0, 4 in q1;
// compiler auto-waitcnt covers the reg deps), cvt+swizzled ds_write_b64 in q2/q3 (T14 split).
// B(kt+1): gl_lds halves in q2/q3 (unchanged). Counted-vmcnt ledger (steady, entering q0
// with [Bg23]=2 outstanding):
//   q0: +A4a -> 6; close vmcnt(4) retires Bg23 (read in q1).
//   q1: +A4b -> 8; close plain.
//   q2: auto-wait retires A4a; ds_write A-half0; +Bg01 -> 6; close plain.
//   q3: auto-wait retires A4b; ds_write A-half1; +Bg23 -> 4; close vmcnt(2) retires Bg01
//       (read in kt+1 q0) + lgkmcnt(0) (cross-wave ds_write visibility) + barrier.
// XOR k-slot swizzle identical to the verified kernels (0 conflicts).
#define PH_OPEN                                                  \
    __builtin_amdgcn_s_barrier();                                \
    asm volatile("s_waitcnt lgkmcnt(0)" ::: "memory");           \
    __builtin_amdgcn_sched_barrier(0);                           \
    __builtin_amdgcn_s_setprio(1)

#define PH_CLOSE                                                 \
    __builtin_amdgcn_s_setprio(0);                               \
    __builtin_amdgcn_sched_barrier(0);                           \
    __builtin_amdgcn_s_barrier();                                \
    __builtin_amdgcn_sched_barrier(0)

#define PH_CLOSE_VM4                                             \
    __builtin_amdgcn_s_setprio(0);                               \
    __builtin_amdgcn_sched_barrier(0);                           \
    asm volatile("s_waitcnt vmcnt(4)" ::: "memory");             \
    __builtin_amdgcn_s_barrier();                                \
    __builtin_amdgcn_sched_barrier(0)

#define PH_CLOSE_VM2_LG0                                         \
    __builtin_amdgcn_s_setprio(0);                               \
    __builtin_amdgcn_sched_barrier(0);                           \
    asm volatile("s_waitcnt vmcnt(2) lgkmcnt(0)" ::: "memory");  \
    __builtin_amdgcn_s_barrier();                                \
    __builtin_amdgcn_sched_barrier(0)

#define PH_CLOSE_VM0                                             \
    __builtin_amdgcn_s_setprio(0);                               \
    __builtin_amdgcn_sched_barrier(0);                           \
    asm volatile("s_waitcnt vmcnt(0)" ::: "memory");             \
    __builtin_amdgcn_s_barrier();                                \
    __builtin_amdgcn_sched_barrier(0)

#define STG_B(NB, H)                                                                      \
    gl_lds16(pb[H][0], &sm[NB][16384 + (H) * 8192 + t * 8]);        pb[H][0] += 64;       \
    gl_lds16(pb[H][1], &sm[NB][16384 + (H) * 8192 + 4096 + t * 8]); pb[H][1] += 64;

// A-tile register staging: thread t owns rows arow+{0,32,...,224}, cols acol..acol+3 (f32).
// 16-lane groups read 256B contiguous per row-segment (coalesced).
#define WR_A(NB, J0)                                                                      \
    _Pragma("unroll") for (int j = (J0); j < (J0) + 4; ++j)                               \
        *(s16x4*)&sm[NB][(arow + j * 32) * 64 + aswz] = cvt4(afv[j]);

#define RD_A(CB, KS)                                                                       \
    _Pragma("unroll") for (int mi = 0; mi < 8; ++mi)                                       \
        afr[mi] = *(const short8*)&sm[CB][(wr * 128 + mi * 16 + l15) * 64 +                \
                                          ((((KS) * 4 + quad) ^ v7) * 8)];

#define RD_B(CB, G, KS)                                                                    \
    (*(const short8*)&sm[CB][16384 + (G) * 4096 + (wc * 16 + l15) * 64 +                   \
                             ((((KS) * 4 + quad) ^ v7) * 8)])

#define MFMA_PAIR(GP)                                                                      \
    _Pragma("unroll") for (int mi = 0; mi < 8; ++mi)                                       \
        acc[mi][2 * (GP)] = __builtin_amdgcn_mfma_f32_16x16x32_bf16(                       \
            afr[mi], b0, acc[mi][2 * (GP)], 0, 0, 0);                                      \
    _Pragma("unroll") for (int mi = 0; mi < 8; ++mi)                                       \
        acc[mi][2 * (GP) + 1] = __builtin_amdgcn_mfma_f32_16x16x32_bf16(                   \
            afr[mi], b1, acc[mi][2 * (GP) + 1], 0, 0, 0);

__global__ __launch_bounds__(512, 2) void lstm_gemm(
    const float* __restrict__ xg, const float* __restrict__ hg,
    const u16* __restrict__ Wt, const float* __restrict__ c_prev,
    const float* __restrict__ bf_, const float* __restrict__ bi_,
    const float* __restrict__ bg_, const float* __restrict__ bo_,
    float* __restrict__ out) {
    // per buffer: [0,16384) A: m*64 + slot*8 ; [16384,32768) B: g*4096 + n*64 + slot*8
    __shared__ u16 sm[2][32768];   // 128 KiB total

    const int t = threadIdx.x;
    const int w = t >> 6;
    const int l = t & 63;
    const int quad = l >> 4;
    const int l15 = l & 15;
    const int v7 = l15 & 7;
    const int wr = w >> 2;          // 0..1: m-half
    const int wc = w & 3;           // 0..3: 16-col slice
    const int m0 = blockIdx.x * 256;
    const int j0 = blockIdx.y * 64;

    // A-staging geometry
    const int arow = t >> 4;                 // 0..31
    const int acol = (t & 15) * 4;           // 0..60
    const int aswz = (((t & 15) >> 1) ^ ((t >> 4) & 7)) * 8 + (t & 1) * 4;  // u16 units

    f32x4 acc[8][4];                // [mi][gate]
#pragma unroll
    for (int mi = 0; mi < 8; ++mi)
#pragma unroll
        for (int g = 0; g < 4; ++g)
            acc[mi][g] = (f32x4){0.f, 0.f, 0.f, 0.f};

    // B staging source pointers, pre-swizzled (advance 64 u16/K-tile). half h = gates {2h,2h+1}.
    const u16* pb[2][2];
#pragma unroll
    for (int h = 0; h < 2; ++h)
#pragma unroll
        for (int i = 0; i < 2; ++i) {
            int e = h * 8192 + (i * 512 + t) * 8;
            int sl = (e >> 3) & 7;
            int g = e >> 12, n = (e >> 6) & 63;
            pb[h][i] = Wt + (size_t)g * ((size_t)H_DIM * K_DIM) + (size_t)(j0 + n) * K_DIM +
                       ((sl ^ (n & 7)) * 8);
        }

    short8 afr[8], b0, b1;
    float4 afv[8];

    // ---- prologue: stage tile 0 into buf 0 ----
    {
        const float4* ab0 = (const float4*)(xg + (size_t)(m0 + arow) * 1024 + acol);
#pragma unroll
        for (int j = 0; j < 8; ++j) afv[j] = ab0[j * 8192];
        STG_B(0, 0); STG_B(0, 1);
        WR_A(0, 0); WR_A(0, 4);    // compiler auto-waits vmcnt for afv regs
        asm volatile("s_waitcnt vmcnt(2) lgkmcnt(0)" ::: "memory");   // Bg01 landed; Bg23 in flight
        __builtin_amdgcn_s_barrier();
        __builtin_amdgcn_sched_barrier(0);
    }

    for (int kt = 0; kt < NTILE - 1; ++kt) {
        const int cb = kt & 1, nb = cb ^ 1;
        const int T = kt + 1;
        const float* srcA = (T < 16) ? xg : hg;
        const float4* abase =
            (const float4*)(srcA + (size_t)(m0 + arow) * 1024 + (T & 15) * 64 + acol);
        // ---- q0: gates 0,1 x ks0 ----
        RD_A(cb, 0);
        b0 = RD_B(cb, 0, 0); b1 = RD_B(cb, 1, 0);
        afv[0] = abase[0]; afv[1] = abase[8192]; afv[2] = abase[16384]; afv[3] = abase[24576];
        PH_OPEN;
        MFMA_PAIR(0);
        PH_CLOSE_VM4;        // retire Bg23(kt) (read in q1); A4a stays in flight
        // ---- q1: gates 2,3 x ks0 ----
        b0 = RD_B(cb, 2, 0); b1 = RD_B(cb, 3, 0);
        afv[4] = abase[32768]; afv[5] = abase[40960]; afv[6] = abase[49152]; afv[7] = abase[57344];
        PH_OPEN;
        MFMA_PAIR(1);
        PH_CLOSE;
        // ---- q2: gates 0,1 x ks1 ----
        RD_A(cb, 1);
        b0 = RD_B(cb, 0, 1); b1 = RD_B(cb, 1, 1);
        WR_A(nb, 0);         // auto-wait retires A4a
        STG_B(nb, 0);
        PH_OPEN;
        MFMA_PAIR(0);
        PH_CLOSE;
        // ---- q3: gates 2,3 x ks1 ----
        b0 = RD_B(cb, 2, 1); b1 = RD_B(cb, 3, 1);
        WR_A(nb, 4);         // auto-wait retires A4b
        STG_B(nb, 1);
        PH_OPEN;
        MFMA_PAIR(1);
        PH_CLOSE_VM2_LG0;    // retire Bg01(kt+1); drain own ds_writes before barrier
    }
    {   // peeled last tile (cb = 1), no staging
        const int cb = (NTILE - 1) & 1;
        RD_A(cb, 0);
        b0 = RD_B(cb, 0, 0); b1 = RD_B(cb, 1, 0);
        PH_OPEN;
        MFMA_PAIR(0);
        PH_CLOSE_VM0;        // only B-g23(last) outstanding -> full drain
        b0 = RD_B(cb, 2, 0); b1 = RD_B(cb, 3, 0);
        PH_OPEN;
        MFMA_PAIR(1);
        PH_CLOSE;
        RD_A(cb, 1);
        b0 = RD_B(cb, 0, 1); b1 = RD_B(cb, 1, 1);
        PH_OPEN;
        MFMA_PAIR(0);
        PH_CLOSE;
        b0 = RD_B(cb, 2, 1); b1 = RD_B(cb, 3, 1);
        asm volatile("s_waitcnt lgkmcnt(0)" ::: "memory");
        __builtin_amdgcn_sched_barrier(0);
        MFMA_PAIR(1);
    }

    // -------- register epilogue: all 4 gates of each output element in one lane --------
    const int col = j0 + wc * 16 + l15;
    const float bF = bf_[col], bI = bi_[col], bG = bg_[col], bO = bo_[col];
#pragma unroll
    for (int mi = 0; mi < 8; ++mi) {
        const int rowbase = m0 + wr * 128 + mi * 16 + quad * 4;   // C/D map: col=lane&15, row=quad*4+reg
        float cp[4];
#pragma unroll
        for (int rr = 0; rr < 4; ++rr)
            cp[rr] = c_prev[(size_t)(rowbase + rr) * H_DIM + col];
#pragma unroll
        for (int rr = 0; rr < 4; ++rr) {
            float fv = sigm(acc[mi][0][rr] + bF);
            float iv = sigm(acc[mi][1][rr] + bI);
            float gv = tanh_f(acc[mi][2][rr] + bG);
            float ov = sigm(acc[mi][3][rr] + bO);
            float cn = fv * cp[rr] + iv * gv;
            float hn = ov * tanh_f(cn);
            size_t idx = (size_t)(rowbase + rr) * H_DIM + col;
            out[idx] = hn;
            out[(size_t)B_DIM * H_DIM + idx] = cn;
        }
    }
}

// ---------- fallback (verified): used only if ws too small ----------
__global__ __launch_bounds__(256) void lstm_f32(
    const float* __restrict__ x, const float* __restrict__ h_prev, const float* __restrict__ c_prev,
    const float* __restrict__ Wf, const float* __restrict__ Wi, const float* __restrict__ Wg, const float* __restrict__ Wo,
    const float* __restrict__ bf_, const float* __restrict__ bi_, const float* __restrict__ bg_, const float* __restrict__ bo_,
    float* __restrict__ out) {
    __shared__ u16 smem[16384];
    u16* sA = smem;
    u16* sB = smem + 4096;

    const int t = threadIdx.x;
    const int w = t >> 6;
    const int l = t & 63;
    const int quad = l >> 4;
    const int l15 = l & 15;
    const int wr = w >> 1;
    const int wc = w & 1;
    const int m0 = blockIdx.x * 128;
    const int j0 = blockIdx.y * 32;

    const int arow = t >> 1;
    const int akh = (t & 1) * 16;
    const int r7 = t & 127;
    const int bk = r7 >> 2;
    const int bn8 = (r7 & 3) * 8;
    const int kswz = ((((bk >> 3) ^ (bn8 >> 3)) << 3) | (bk & 7));
    const float* WpA = (t < 128) ? Wf : Wi;
    const float* WpB = (t < 128) ? Wg : Wo;
    const int gA = (t >> 7);
    const int gB = 2 + (t >> 7);

    f32x4 acc[2][4][2];
#pragma unroll
    for (int gi = 0; gi < 2; ++gi)
#pragma unroll
        for (int mi = 0; mi < 4; ++mi)
#pragma unroll
            for (int ni = 0; ni < 2; ++ni)
                acc[gi][mi][ni] = (f32x4){0.f, 0.f, 0.f, 0.f};

    for (int kt = 0; kt < K_DIM / 32; ++kt) {
        const float* srcA = (kt < 32) ? x : h_prev;
        const int koff = (kt & 31) * 32;
        __syncthreads();

        const float4* ap = (const float4*)(srcA + (size_t)(m0 + arow) * H_DIM + koff + akh);
        float4 a0 = ap[0], a1 = ap[1], a2 = ap[2], a3 = ap[3];
        short8 p0, p1;
        p0[0] = (short)f2bf(a0.x); p0[1] = (short)f2bf(a0.y); p0[2] = (short)f2bf(a0.z); p0[3] = (short)f2bf(a0.w);
        p0[4] = (short)f2bf(a1.x); p0[5] = (short)f2bf(a1.y); p0[6] = (short)f2bf(a1.z); p0[7] = (short)f2bf(a1.w);
        p1[0] = (short)f2bf(a2.x); p1[1] = (short)f2bf(a2.y); p1[2] = (short)f2bf(a2.z); p1[3] = (short)f2bf(a2.w);
        p1[4] = (short)f2bf(a3.x); p1[5] = (short)f2bf(a3.y); p1[6] = (short)f2bf(a3.z); p1[7] = (short)f2bf(a3.w);
        *(short8*)(sA + arow * 32 + akh) = p0;
        *(short8*)(sA + arow * 32 + akh + 8) = p1;

        const float* gpA = WpA + (size_t)(kt * 32 + bk) * H_DIM + j0 + bn8;
        const float* gpB = WpB + (size_t)(kt * 32 + bk) * H_DIM + j0 + bn8;
        float4 c0 = *(const float4*)gpA, c1 = *(const float4*)(gpA + 4);
        float4 d0 = *(const float4*)gpB, d1 = *(const float4*)(gpB + 4);
        sB[gA * 1024 + (bn8 + 0) * 32 + kswz] = f2bf(c0.x);
        sB[gA * 1024 + (bn8 + 1) * 32 + kswz] = f2bf(c0.y);
        sB[gA * 1024 + (bn8 + 2) * 32 + kswz] = f2bf(c0.z);
        sB[gA * 1024 + (bn8 + 3) * 32 + kswz] = f2bf(c0.w);
        sB[gA * 1024 + (bn8 + 4) * 32 + kswz] = f2bf(c1.x);
        sB[gA * 1024 + (bn8 + 5) * 32 + kswz] = f2bf(c1.y);
        sB[gA * 1024 + (bn8 + 6) * 32 + kswz] = f2bf(c1.z);
        sB[gA * 1024 + (bn8 + 7) * 32 + kswz] = f2bf(c1.w);
        sB[gB * 1024 + (bn8 + 0) * 32 + kswz] = f2bf(d0.x);
        sB[gB * 1024 + (bn8 + 1) * 32 + kswz] = f2bf(d0.y);
        sB[gB * 1024 + (bn8 + 2) * 32 + kswz] = f2bf(d0.z);
        sB[gB * 1024 + (bn8 + 3) * 32 + kswz] = f2bf(d0.w);
        sB[gB * 1024 + (bn8 + 4) * 32 + kswz] = f2bf(d1.x);
        sB[gB * 1024 + (bn8 + 5) * 32 + kswz] = f2bf(d1.y);
        sB[gB * 1024 + (bn8 + 6) * 32 + kswz] = f2bf(d1.z);
        sB[gB * 1024 + (bn8 + 7) * 32 + kswz] = f2bf(d1.w);
        __syncthreads();

        short8 bfr[2][2];
#pragma unroll
        for (int gi = 0; gi < 2; ++gi) {
            int g = wc * 2 + gi;
#pragma unroll
            for (int ni = 0; ni < 2; ++ni) {
                int n = ni * 16 + l15;
                bfr[gi][ni] = *(const short8*)(sB + g * 1024 + n * 32 + ((quad ^ (n >> 3)) * 8));
            }
        }
#pragma unroll
        for (int mi = 0; mi < 4; ++mi) {
            int m = wr * 64 + mi * 16 + l15;
            short8 afr = *(const short8*)(sA + m * 32 + quad * 8);
#pragma unroll
            for (int gi = 0; gi < 2; ++gi)
#pragma unroll
                for (int ni = 0; ni < 2; ++ni)
                    acc[gi][mi][ni] =
                        __builtin_amdgcn_mfma_f32_16x16x32_bf16(afr, bfr[gi][ni], acc[gi][mi][ni], 0, 0, 0);
        }
    }

    __syncthreads();
#pragma unroll
    for (int gi = 0; gi < 2; ++gi) {
        int g = wc * 2 + gi;
        const float* bp = (g == 0) ? bf_ : (g == 1) ? bi_ : (g == 2) ? bg_ : bo_;
#pragma unroll
        for (int ni = 0; ni < 2; ++ni) {
            int col = ni * 16 + l15;
            float bias = bp[j0 + col];
#pragma unroll
            for (int mi = 0; mi < 4; ++mi)
#pragma unroll
                for (int rr = 0; rr < 4; ++rr) {
                    int row = wr * 64 + mi * 16 + quad * 4 + rr;
                    float v = acc[gi][mi][ni][rr] + bias;
                    v = (g == 2) ? tanh_f(v) : sigm(v);
                    smem[g * 4096 + row * 32 + col] = f2bf(v);
                }
        }
    }
    __syncthreads();

    const int col = t & 31;
    const int rb = t >> 5;
#pragma unroll
    for (int p = 0; p < 16; ++p) {
        int row = p * 8 + rb;
        float fv = bf2f(smem[0 * 4096 + row * 32 + col]);
        float iv = bf2f(smem[1 * 4096 + row * 32 + col]);
        float gv = bf2f(smem[2 * 4096 + row * 32 + col]);
        float ov = bf2f(smem[3 * 4096 + row * 32 + col]);
        size_t oidx = (size_t)(m0 + row) * H_DIM + j0 + col;
        float cp = c_prev[oidx];
        float cn = fv * cp + iv * gv;
        float hn = ov * tanh_f(cn);
        out[oidx] = hn;
        out[(size_t)B_DIM * H_DIM + oidx] = cn;
    }
}

extern "C" void kernel_launch(void* const* d_in, const int* in_sizes, int n_in,
                              void* d_out, int out_size, void* d_ws, size_t ws_size,
                              hipStream_t stream) {
    const float* x   = (const float*)d_in[0];
    const float* hp  = (const float*)d_in[1];
    const float* cp  = (const float*)d_in[2];
    const float* Wf  = (const float*)d_in[3];
    const float* bf_ = (const float*)d_in[4];
    const float* Wi  = (const float*)d_in[5];
    const float* bi_ = (const float*)d_in[6];
    const float* Wg  = (const float*)d_in[7];
    const float* bg_ = (const float*)d_in[8];
    const float* Wo  = (const float*)d_in[9];
    const float* bo_ = (const float*)d_in[10];

    if (ws_size >= WS_NEEDED) {
        u16* Wt = (u16*)d_ws;
        prep_W<<<dim3(512), dim3(256), 0, stream>>>(Wf, Wi, Wg, Wo, Wt);
        lstm_gemm<<<dim3(B_DIM / 256, H_DIM / 64), dim3(512), 0, stream>>>(
            x, hp, Wt, cp, bf_, bi_, bg_, bo_, (float*)d_out);
    } else {
        lstm_f32<<<dim3(B_DIM / 128, H_DIM / 32), dim3(256), 0, stream>>>(
            x, hp, cp, Wf, Wi, Wg, Wo, bf_, bi_, bg_, bo_, (float*)d_out);
    }
}

// Round 5
// 199.059 us; speedup vs baseline: 1.2405x; 1.2405x over previous
//
#include <hip/hip_runtime.h>

#define B_DIM 4096
#define H_DIM 1024
#define K_DIM 2048   // IN + H
#define NTILE (K_DIM / 64)

typedef unsigned short u16;
typedef unsigned int u32;
typedef __attribute__((ext_vector_type(8))) short short8;
typedef __attribute__((ext_vector_type(4))) float f32x4;

typedef const __attribute__((address_space(1))) void* gas_ptr;
typedef __attribute__((address_space(3))) void* las_ptr;

#define WT_ELEMS (4 * H_DIM * K_DIM)       // 8.39M u16
#define AC_ELEMS (B_DIM * K_DIM)           // 8.39M u16
#define WS_NEEDED ((size_t)(WT_ELEMS + AC_ELEMS) * 2)   // 33.55 MB

__device__ __forceinline__ void gl_lds16(const u16* g, u16* l) {
    __builtin_amdgcn_global_load_lds((gas_ptr)g, (las_ptr)l, 16, 0, 0);
}
__device__ __forceinline__ float bf2f(u16 v) {
    return __builtin_bit_cast(float, (u32)((u32)v << 16));
}
__device__ __forceinline__ u16 f2bf(float f) {
    u32 u = __builtin_bit_cast(u32, f);
    return (u16)((u + 0x7fffu + ((u >> 16) & 1u)) >> 16);
}
__device__ __forceinline__ float sigm(float x) { return 1.0f / (1.0f + __expf(-x)); }
__device__ __forceinline__ float tanh_f(float x) { return 1.0f - 2.0f / (__expf(2.0f * x) + 1.0f); }

// ---------- consolidated prep: 1024 blocks ----------
// blocks [0,512):   A-convert, grid-strided x8 (each thread: 8 x {32B f32 load -> 16B bf16 store})
// blocks [512,1024): W-transpose, register-only 8x8 per lane (r2/r3-verified), 4 tiles/block
// Balanced per-thread work: both halves load 256B + store 128B.
__global__ __launch_bounds__(256) void prep_all(const float* __restrict__ x, const float* __restrict__ h,
                                                const float* __restrict__ Wf, const float* __restrict__ Wi,
                                                const float* __restrict__ Wg, const float* __restrict__ Wo,
                                                u16* __restrict__ A, u16* __restrict__ Wt) {
    const int t = threadIdx.x;
    if (blockIdx.x < 512) {
#pragma unroll
        for (int it = 0; it < 8; ++it) {
            int e = it * (512 * 256 * 8) + (blockIdx.x * 256 + t) * 8;
            int m = e >> 11, c = e & 2047;
            const float* src = (c < 1024) ? (x + (size_t)m * 1024 + c)
                                          : (h + (size_t)m * 1024 + (c - 1024));
            float4 v0 = ((const float4*)src)[0], v1 = ((const float4*)src)[1];
            short8 q;
            q[0] = (short)f2bf(v0.x); q[1] = (short)f2bf(v0.y); q[2] = (short)f2bf(v0.z); q[3] = (short)f2bf(v0.w);
            q[4] = (short)f2bf(v1.x); q[5] = (short)f2bf(v1.y); q[6] = (short)f2bf(v1.z); q[7] = (short)f2bf(v1.w);
            *(short8*)(A + e) = q;
        }
    } else {
        const int id = (blockIdx.x - 512) * 4 + (t >> 6);   // one 64x64 tile per wave
        const int l = t & 63;
        const int k0 = (id & 31) * 64, n0 = ((id >> 5) & 15) * 64, g = id >> 9;
        const float* W = (g == 0) ? Wf : (g == 1) ? Wi : (g == 2) ? Wg : Wo;
        const int no = (l & 7) * 8;
        const int ko = (l >> 3) * 8;
        float f[8][8];
#pragma unroll
        for (int j = 0; j < 8; ++j) {
            const float4* s = (const float4*)(W + (size_t)(k0 + ko + j) * H_DIM + n0 + no);
            float4 a = s[0], b = s[1];
            f[j][0] = a.x; f[j][1] = a.y; f[j][2] = a.z; f[j][3] = a.w;
            f[j][4] = b.x; f[j][5] = b.y; f[j][6] = b.z; f[j][7] = b.w;
        }
        u16* dst0 = Wt + (size_t)g * ((size_t)H_DIM * K_DIM) + (size_t)(n0 + no) * K_DIM + k0 + ko;
#pragma unroll
        for (int w2 = 0; w2 < 8; ++w2) {
            short8 q;
#pragma unroll
            for (int j = 0; j < 8; ++j) q[j] = (short)f2bf(f[j][w2]);
            *(short8*)(dst0 + (size_t)w2 * K_DIM) = q;
        }
    }
}

// ---------- main fused GEMM + LSTM: 8-phase counted-vmcnt schedule (round-3 verified, 79.5 us) ----------
// Block: 256 m-rows x (4 gates x 64 H-cols), 512 thr = 8 waves (2 wr x 4 wc). BK=64,
// 128 KiB double-buffered LDS, grid 16x16 = 256 blocks, zero tail.
// Per K-tile: 4 phases x {ds_read frags; issue gl_lds; barrier; lgkmcnt(0); setprio(1);
// 16 MFMA; setprio(0); barrier}. vmcnt(2) only at the two boundary phases.
// XOR k-slot swizzle (0 conflicts, verified).
#define PH_OPEN                                                  \
    __builtin_amdgcn_s_barrier();                                \
    asm volatile("s_waitcnt lgkmcnt(0)" ::: "memory");           \
    __builtin_amdgcn_sched_barrier(0);                           \
    __builtin_amdgcn_s_setprio(1)

#define PH_CLOSE                                                 \
    __builtin_amdgcn_s_setprio(0);                               \
    __builtin_amdgcn_sched_barrier(0);                           \
    __builtin_amdgcn_s_barrier();                                \
    __builtin_amdgcn_sched_barrier(0)

#define PH_CLOSE_VM2                                             \
    __builtin_amdgcn_s_setprio(0);                               \
    __builtin_amdgcn_sched_barrier(0);                           \
    asm volatile("s_waitcnt vmcnt(2)" ::: "memory");             \
    __builtin_amdgcn_s_barrier();                                \
    __builtin_amdgcn_sched_barrier(0)

#define PH_CLOSE_VM0                                             \
    __builtin_amdgcn_s_setprio(0);                               \
    __builtin_amdgcn_sched_barrier(0);                           \
    asm volatile("s_waitcnt vmcnt(0)" ::: "memory");             \
    __builtin_amdgcn_s_barrier();                                \
    __builtin_amdgcn_sched_barrier(0)

#define STG_A(NB, H)                                                              \
    gl_lds16(pa[H][0], &sm[NB][(H) * 8192 + t * 8]);        pa[H][0] += 64;       \
    gl_lds16(pa[H][1], &sm[NB][(H) * 8192 + 4096 + t * 8]); pa[H][1] += 64;

#define STG_B(NB, H)                                                                      \
    gl_lds16(pb[H][0], &sm[NB][16384 + (H) * 8192 + t * 8]);        pb[H][0] += 64;       \
    gl_lds16(pb[H][1], &sm[NB][16384 + (H) * 8192 + 4096 + t * 8]); pb[H][1] += 64;

#define RD_A(CB, KS)                                                                       \
    _Pragma("unroll") for (int mi = 0; mi < 8; ++mi)                                       \
        afr[mi] = *(const short8*)&sm[CB][(wr * 128 + mi * 16 + l15) * 64 +                \
                                          ((((KS) * 4 + quad) ^ v7) * 8)];

#define RD_B(CB, G, KS)                                                                    \
    (*(const short8*)&sm[CB][16384 + (G) * 4096 + (wc * 16 + l15) * 64 +                   \
                             ((((KS) * 4 + quad) ^ v7) * 8)])

#define MFMA_PAIR(GP)                                                                      \
    _Pragma("unroll") for (int mi = 0; mi < 8; ++mi)                                       \
        acc[mi][2 * (GP)] = __builtin_amdgcn_mfma_f32_16x16x32_bf16(                       \
            afr[mi], b0, acc[mi][2 * (GP)], 0, 0, 0);                                      \
    _Pragma("unroll") for (int mi = 0; mi < 8; ++mi)                                       \
        acc[mi][2 * (GP) + 1] = __builtin_amdgcn_mfma_f32_16x16x32_bf16(                   \
            afr[mi], b1, acc[mi][2 * (GP) + 1], 0, 0, 0);

__global__ __launch_bounds__(512, 2) void lstm_gemm(
    const u16* __restrict__ A, const u16* __restrict__ Wt, const float* __restrict__ c_prev,
    const float* __restrict__ bf_, const float* __restrict__ bi_,
    const float* __restrict__ bg_, const float* __restrict__ bo_,
    float* __restrict__ out) {
    // per buffer: [0,16384) A: m*64 + slot*8 ; [16384,32768) B: g*4096 + n*64 + slot*8
    __shared__ u16 sm[2][32768];   // 128 KiB total

    const int t = threadIdx.x;
    const int w = t >> 6;
    const int l = t & 63;
    const int quad = l >> 4;
    const int l15 = l & 15;
    const int v7 = l15 & 7;
    const int wr = w >> 2;          // 0..1: m-half
    const int wc = w & 3;           // 0..3: 16-col slice
    const int m0 = blockIdx.x * 256;
    const int j0 = blockIdx.y * 64;

    f32x4 acc[8][4];                // [mi][gate]
#pragma unroll
    for (int mi = 0; mi < 8; ++mi)
#pragma unroll
        for (int g = 0; g < 4; ++g)
            acc[mi][g] = (f32x4){0.f, 0.f, 0.f, 0.f};

    // Staging source pointers, pre-swizzled (advance by 64 u16 per K-tile).
    // A half h = m-rows [h*128, h*128+128); B half h = gates {2h, 2h+1}.
    const u16* pa[2][2];
    const u16* pb[2][2];
#pragma unroll
    for (int h = 0; h < 2; ++h)
#pragma unroll
        for (int i = 0; i < 2; ++i) {
            int e = h * 8192 + (i * 512 + t) * 8;
            int m = e >> 6, sl = (e >> 3) & 7;
            pa[h][i] = A + (size_t)(m0 + m) * K_DIM + ((sl ^ (m & 7)) * 8);
            int g = e >> 12, n = (e >> 6) & 63;
            pb[h][i] = Wt + (size_t)g * ((size_t)H_DIM * K_DIM) + (size_t)(j0 + n) * K_DIM +
                       ((sl ^ (n & 7)) * 8);
        }

    short8 afr[8], b0, b1;

    // prologue: stage tile 0 into buf 0 (issue order: A-h0, A-h1, B-g01, B-g23)
    STG_A(0, 0); STG_A(0, 1); STG_B(0, 0); STG_B(0, 1);
    asm volatile("s_waitcnt vmcnt(2)" ::: "memory");   // A + B-g01 landed; B-g23 in flight
    __builtin_amdgcn_s_barrier();
    __builtin_amdgcn_sched_barrier(0);

    for (int kt = 0; kt < NTILE - 1; ++kt) {
        const int cb = kt & 1, nb = cb ^ 1;
        // ---- q0: gates 0,1 x ks0 ----
        RD_A(cb, 0);
        b0 = RD_B(cb, 0, 0); b1 = RD_B(cb, 1, 0);
        STG_A(nb, 0);
        PH_OPEN;
        MFMA_PAIR(0);
        PH_CLOSE_VM2;        // B-g23(kt) landed; A-h0(kt+1) in flight
        // ---- q1: gates 2,3 x ks0 ----
        b0 = RD_B(cb, 2, 0); b1 = RD_B(cb, 3, 0);
        STG_A(nb, 1);
        PH_OPEN;
        MFMA_PAIR(1);
        PH_CLOSE;
        // ---- q2: gates 0,1 x ks1 ----
        RD_A(cb, 1);
        b0 = RD_B(cb, 0, 1); b1 = RD_B(cb, 1, 1);
        STG_B(nb, 0);
        PH_OPEN;
        MFMA_PAIR(0);
        PH_CLOSE;
        // ---- q3: gates 2,3 x ks1 ----
        b0 = RD_B(cb, 2, 1); b1 = RD_B(cb, 3, 1);
        STG_B(nb, 1);
        PH_OPEN;
        MFMA_PAIR(1);
        PH_CLOSE_VM2;        // A(kt+1) + B-g01(kt+1) landed; B-g23(kt+1) in flight
    }
    {   // peeled last tile (cb = 1), no staging
        const int cb = (NTILE - 1) & 1;
        RD_A(cb, 0);
        b0 = RD_B(cb, 0, 0); b1 = RD_B(cb, 1, 0);
        PH_OPEN;
        MFMA_PAIR(0);
        PH_CLOSE_VM0;        // only B-g23(last) outstanding -> full drain
        b0 = RD_B(cb, 2, 0); b1 = RD_B(cb, 3, 0);
        PH_OPEN;
        MFMA_PAIR(1);
        PH_CLOSE;
        RD_A(cb, 1);
        b0 = RD_B(cb, 0, 1); b1 = RD_B(cb, 1, 1);
        PH_OPEN;
        MFMA_PAIR(0);
        PH_CLOSE;
        b0 = RD_B(cb, 2, 1); b1 = RD_B(cb, 3, 1);
        asm volatile("s_waitcnt lgkmcnt(0)" ::: "memory");
        __builtin_amdgcn_sched_barrier(0);
        MFMA_PAIR(1);
    }

    // -------- register epilogue: all 4 gates of each output element in one lane --------
    const int col = j0 + wc * 16 + l15;
    const float bF = bf_[col], bI = bi_[col], bG = bg_[col], bO = bo_[col];
#pragma unroll
    for (int mi = 0; mi < 8; ++mi) {
        const int rowbase = m0 + wr * 128 + mi * 16 + quad * 4;   // C/D map: col=lane&15, row=quad*4+reg
        float cp[4];
#pragma unroll
        for (int rr = 0; rr < 4; ++rr)
            cp[rr] = c_prev[(size_t)(rowbase + rr) * H_DIM + col];
#pragma unroll
        for (int rr = 0; rr < 4; ++rr) {
            float fv = sigm(acc[mi][0][rr] + bF);
            float iv = sigm(acc[mi][1][rr] + bI);
            float gv = tanh_f(acc[mi][2][rr] + bG);
            float ov = sigm(acc[mi][3][rr] + bO);
            float cn = fv * cp[rr] + iv * gv;
            float hn = ov * tanh_f(cn);
            size_t idx = (size_t)(rowbase + rr) * H_DIM + col;
            out[idx] = hn;
            out[(size_t)B_DIM * H_DIM + idx] = cn;
        }
    }
}

// ---------- fallback (verified): used only if ws too small ----------
__global__ __launch_bounds__(256) void lstm_f32(
    const float* __restrict__ x, const float* __restrict__ h_prev, const float* __restrict__ c_prev,
    const float* __restrict__ Wf, const float* __restrict__ Wi, const float* __restrict__ Wg, const float* __restrict__ Wo,
    const float* __restrict__ bf_, const float* __restrict__ bi_, const float* __restrict__ bg_, const float* __restrict__ bo_,
    float* __restrict__ out) {
    __shared__ u16 smem[16384];
    u16* sA = smem;
    u16* sB = smem + 4096;

    const int t = threadIdx.x;
    const int w = t >> 6;
    const int l = t & 63;
    const int quad = l >> 4;
    const int l15 = l & 15;
    const int wr = w >> 1;
    const int wc = w & 1;
    const int m0 = blockIdx.x * 128;
    const int j0 = blockIdx.y * 32;

    const int arow = t >> 1;
    const int akh = (t & 1) * 16;
    const int r7 = t & 127;
    const int bk = r7 >> 2;
    const int bn8 = (r7 & 3) * 8;
    const int kswz = ((((bk >> 3) ^ (bn8 >> 3)) << 3) | (bk & 7));
    const float* WpA = (t < 128) ? Wf : Wi;
    const float* WpB = (t < 128) ? Wg : Wo;
    const int gA = (t >> 7);
    const int gB = 2 + (t >> 7);

    f32x4 acc[2][4][2];
#pragma unroll
    for (int gi = 0; gi < 2; ++gi)
#pragma unroll
        for (int mi = 0; mi < 4; ++mi)
#pragma unroll
            for (int ni = 0; ni < 2; ++ni)
                acc[gi][mi][ni] = (f32x4){0.f, 0.f, 0.f, 0.f};

    for (int kt = 0; kt < K_DIM / 32; ++kt) {
        const float* srcA = (kt < 32) ? x : h_prev;
        const int koff = (kt & 31) * 32;
        __syncthreads();

        const float4* ap = (const float4*)(srcA + (size_t)(m0 + arow) * H_DIM + koff + akh);
        float4 a0 = ap[0], a1 = ap[1], a2 = ap[2], a3 = ap[3];
        short8 p0, p1;
        p0[0] = (short)f2bf(a0.x); p0[1] = (short)f2bf(a0.y); p0[2] = (short)f2bf(a0.z); p0[3] = (short)f2bf(a0.w);
        p0[4] = (short)f2bf(a1.x); p0[5] = (short)f2bf(a1.y); p0[6] = (short)f2bf(a1.z); p0[7] = (short)f2bf(a1.w);
        p1[0] = (short)f2bf(a2.x); p1[1] = (short)f2bf(a2.y); p1[2] = (short)f2bf(a2.z); p1[3] = (short)f2bf(a2.w);
        p1[4] = (short)f2bf(a3.x); p1[5] = (short)f2bf(a3.y); p1[6] = (short)f2bf(a3.z); p1[7] = (short)f2bf(a3.w);
        *(short8*)(sA + arow * 32 + akh) = p0;
        *(short8*)(sA + arow * 32 + akh + 8) = p1;

        const float* gpA = WpA + (size_t)(kt * 32 + bk) * H_DIM + j0 + bn8;
        const float* gpB = WpB + (size_t)(kt * 32 + bk) * H_DIM + j0 + bn8;
        float4 c0 = *(const float4*)gpA, c1 = *(const float4*)(gpA + 4);
        float4 d0 = *(const float4*)gpB, d1 = *(const float4*)(gpB + 4);
        sB[gA * 1024 + (bn8 + 0) * 32 + kswz] = f2bf(c0.x);
        sB[gA * 1024 + (bn8 + 1) * 32 + kswz] = f2bf(c0.y);
        sB[gA * 1024 + (bn8 + 2) * 32 + kswz] = f2bf(c0.z);
        sB[gA * 1024 + (bn8 + 3) * 32 + kswz] = f2bf(c0.w);
        sB[gA * 1024 + (bn8 + 4) * 32 + kswz] = f2bf(c1.x);
        sB[gA * 1024 + (bn8 + 5) * 32 + kswz] = f2bf(c1.y);
        sB[gA * 1024 + (bn8 + 6) * 32 + kswz] = f2bf(c1.z);
        sB[gA * 1024 + (bn8 + 7) * 32 + kswz] = f2bf(c1.w);
        sB[gB * 1024 + (bn8 + 0) * 32 + kswz] = f2bf(d0.x);
        sB[gB * 1024 + (bn8 + 1) * 32 + kswz] = f2bf(d0.y);
        sB[gB * 1024 + (bn8 + 2) * 32 + kswz] = f2bf(d0.z);
        sB[gB * 1024 + (bn8 + 3) * 32 + kswz] = f2bf(d0.w);
        sB[gB * 1024 + (bn8 + 4) * 32 + kswz] = f2bf(d1.x);
        sB[gB * 1024 + (bn8 + 5) * 32 + kswz] = f2bf(d1.y);
        sB[gB * 1024 + (bn8 + 6) * 32 + kswz] = f2bf(d1.z);
        sB[gB * 1024 + (bn8 + 7) * 32 + kswz] = f2bf(d1.w);
        __syncthreads();

        short8 bfr[2][2];
#pragma unroll
        for (int gi = 0; gi < 2; ++gi) {
            int g = wc * 2 + gi;
#pragma unroll
            for (int ni = 0; ni < 2; ++ni) {
                int n = ni * 16 + l15;
                bfr[gi][ni] = *(const short8*)(sB + g * 1024 + n * 32 + ((quad ^ (n >> 3)) * 8));
            }
        }
#pragma unroll
        for (int mi = 0; mi < 4; ++mi) {
            int m = wr * 64 + mi * 16 + l15;
            short8 afr = *(const short8*)(sA + m * 32 + quad * 8);
#pragma unroll
            for (int gi = 0; gi < 2; ++gi)
#pragma unroll
                for (int ni = 0; ni < 2; ++ni)
                    acc[gi][mi][ni] =
                        __builtin_amdgcn_mfma_f32_16x16x32_bf16(afr, bfr[gi][ni], acc[gi][mi][ni], 0, 0, 0);
        }
    }

    __syncthreads();
#pragma unroll
    for (int gi = 0; gi < 2; ++gi) {
        int g = wc * 2 + gi;
        const float* bp = (g == 0) ? bf_ : (g == 1) ? bi_ : (g == 2) ? bg_ : bo_;
#pragma unroll
        for (int ni = 0; ni < 2; ++ni) {
            int col = ni * 16 + l15;
            float bias = bp[j0 + col];
#pragma unroll
            for (int mi = 0; mi < 4; ++mi)
#pragma unroll
                for (int rr = 0; rr < 4; ++rr) {
                    int row = wr * 64 + mi * 16 + quad * 4 + rr;
                    float v = acc[gi][mi][ni][rr] + bias;
                    v = (g == 2) ? tanh_f(v) : sigm(v);
                    smem[g * 4096 + row * 32 + col] = f2bf(v);
                }
        }
    }
    __syncthreads();

    const int col = t & 31;
    const int rb = t >> 5;
#pragma unroll
    for (int p = 0; p < 16; ++p) {
        int row = p * 8 + rb;
        float fv = bf2f(smem[0 * 4096 + row * 32 + col]);
        float iv = bf2f(smem[1 * 4096 + row * 32 + col]);
        float gv = bf2f(smem[2 * 4096 + row * 32 + col]);
        float ov = bf2f(smem[3 * 4096 + row * 32 + col]);
        size_t oidx = (size_t)(m0 + row) * H_DIM + j0 + col;
        float cp = c_prev[oidx];
        float cn = fv * cp + iv * gv;
        float hn = ov * tanh_f(cn);
        out[oidx] = hn;
        out[(size_t)B_DIM * H_DIM + oidx] = cn;
    }
}

extern "C" void kernel_launch(void* const* d_in, const int* in_sizes, int n_in,
                              void* d_out, int out_size, void* d_ws, size_t ws_size,
                              hipStream_t stream) {
    const float* x   = (const float*)d_in[0];
    const float* hp  = (const float*)d_in[1];
    const float* cp  = (const float*)d_in[2];
    const float* Wf  = (const float*)d_in[3];
    const float* bf_ = (const float*)d_in[4];
    const float* Wi  = (const float*)d_in[5];
    const float* bi_ = (const float*)d_in[6];
    const float* Wg  = (const float*)d_in[7];
    const float* bg_ = (const float*)d_in[8];
    const float* Wo  = (const float*)d_in[9];
    const float* bo_ = (const float*)d_in[10];

    if (ws_size >= WS_NEEDED) {
        u16* Wt = (u16*)d_ws;
        u16* Ac = (u16*)d_ws + WT_ELEMS;
        prep_all<<<dim3(1024), dim3(256), 0, stream>>>(x, hp, Wf, Wi, Wg, Wo, Ac, Wt);
        lstm_gemm<<<dim3(B_DIM / 256, H_DIM / 64), dim3(512), 0, stream>>>(
            Ac, Wt, cp, bf_, bi_, bg_, bo_, (float*)d_out);
    } else {
        lstm_f32<<<dim3(B_DIM / 128, H_DIM / 32), dim3(256), 0, stream>>>(
            x, hp, cp, Wf, Wi, Wg, Wo, bf_, bi_, bg_, bo_, (float*)d_out);
    }
}

// Round 6
// 197.765 us; speedup vs baseline: 1.2486x; 1.0065x over previous
//
#include <hip/hip_runtime.h>

#define B_DIM 4096
#define H_DIM 1024
#define K_DIM 2048   // IN + H
#define NTILE (K_DIM / 64)

typedef unsigned short u16;
typedef unsigned int u32;
typedef __attribute__((ext_vector_type(8))) short short8;
typedef __attribute__((ext_vector_type(4))) float f32x4;

typedef const __attribute__((address_space(1))) void* gas_ptr;
typedef __attribute__((address_space(3))) void* las_ptr;

#define WT_ELEMS (4 * H_DIM * K_DIM)       // 8.39M u16
#define AC_ELEMS (B_DIM * K_DIM)           // 8.39M u16
#define WS_NEEDED ((size_t)(WT_ELEMS + AC_ELEMS) * 2)   // 33.55 MB

__device__ __forceinline__ void gl_lds16(const u16* g, u16* l) {
    __builtin_amdgcn_global_load_lds((gas_ptr)g, (las_ptr)l, 16, 0, 0);
}
__device__ __forceinline__ float bf2f(u16 v) {
    return __builtin_bit_cast(float, (u32)((u32)v << 16));
}
__device__ __forceinline__ u16 f2bf(float f) {
    u32 u = __builtin_bit_cast(u32, f);
    return (u16)((u + 0x7fffu + ((u >> 16) & 1u)) >> 16);
}
__device__ __forceinline__ float sigm(float x) { return 1.0f / (1.0f + __expf(-x)); }
__device__ __forceinline__ float tanh_f(float x) { return 1.0f - 2.0f / (__expf(2.0f * x) + 1.0f); }

// ---------- consolidated prep (round-5 verified): 1024 blocks ----------
__global__ __launch_bounds__(256) void prep_all(const float* __restrict__ x, const float* __restrict__ h,
                                                const float* __restrict__ Wf, const float* __restrict__ Wi,
                                                const float* __restrict__ Wg, const float* __restrict__ Wo,
                                                u16* __restrict__ A, u16* __restrict__ Wt) {
    const int t = threadIdx.x;
    if (blockIdx.x < 512) {
#pragma unroll
        for (int it = 0; it < 8; ++it) {
            int e = it * (512 * 256 * 8) + (blockIdx.x * 256 + t) * 8;
            int m = e >> 11, c = e & 2047;
            const float* src = (c < 1024) ? (x + (size_t)m * 1024 + c)
                                          : (h + (size_t)m * 1024 + (c - 1024));
            float4 v0 = ((const float4*)src)[0], v1 = ((const float4*)src)[1];
            short8 q;
            q[0] = (short)f2bf(v0.x); q[1] = (short)f2bf(v0.y); q[2] = (short)f2bf(v0.z); q[3] = (short)f2bf(v0.w);
            q[4] = (short)f2bf(v1.x); q[5] = (short)f2bf(v1.y); q[6] = (short)f2bf(v1.z); q[7] = (short)f2bf(v1.w);
            *(short8*)(A + e) = q;
        }
    } else {
        const int id = (blockIdx.x - 512) * 4 + (t >> 6);   // one 64x64 tile per wave
        const int l = t & 63;
        const int k0 = (id & 31) * 64, n0 = ((id >> 5) & 15) * 64, g = id >> 9;
        const float* W = (g == 0) ? Wf : (g == 1) ? Wi : (g == 2) ? Wg : Wo;
        const int no = (l & 7) * 8;
        const int ko = (l >> 3) * 8;
        float f[8][8];
#pragma unroll
        for (int j = 0; j < 8; ++j) {
            const float4* s = (const float4*)(W + (size_t)(k0 + ko + j) * H_DIM + n0 + no);
            float4 a = s[0], b = s[1];
            f[j][0] = a.x; f[j][1] = a.y; f[j][2] = a.z; f[j][3] = a.w;
            f[j][4] = b.x; f[j][5] = b.y; f[j][6] = b.z; f[j][7] = b.w;
        }
        u16* dst0 = Wt + (size_t)g * ((size_t)H_DIM * K_DIM) + (size_t)(n0 + no) * K_DIM + k0 + ko;
#pragma unroll
        for (int w2 = 0; w2 < 8; ++w2) {
            short8 q;
#pragma unroll
            for (int j = 0; j < 8; ++j) q[j] = (short)f2bf(f[j][w2]);
            *(short8*)(dst0 + (size_t)w2 * K_DIM) = q;
        }
    }
}

// ---------- main fused GEMM + LSTM: 8-phase counted-vmcnt, MINIMAL PINNING ----------
// Same structure/geometry/ledger as the round-3 verified kernel (passed, 79.5 us), but:
//  - NO sched_barrier(0) except one anti-sink pin after q3's MFMA cluster (keeps the
//    register-only MFMAs + their ds_reads from sinking past the tile-boundary barrier
//    into the region where buffer cb is overwritten -- m214-r263 motion class).
//  - NO manual lgkmcnt(0): compiler tracks ds_read->MFMA register deps and emits
//    laddered lgkmcnt(N) so the first MFMA starts when its OWN operands land, and it
//    may hoist phase p+1's ds_reads above phase p's MFMA cluster (plain s_barrier is
//    not a compiler memory fence; the asm vmcnt closes with "memory" clobber remain
//    the publish fences, so no read can hoist above a publish point).
// vmcnt ledger unchanged: enter kt with [Bg23(kt)]=2; q0 +Ah0 -> close vm2 retires
// Bg23(kt); q1 +Ah1; q2 +Bg01; q3 +Bg23 -> close vm2 retires Ah0/Ah1/Bg01(kt+1).
#define PH_OPEN                                                  \
    __builtin_amdgcn_s_barrier();                                \
    __builtin_amdgcn_s_setprio(1)

#define PH_CLOSE                                                 \
    __builtin_amdgcn_s_setprio(0);                               \
    __builtin_amdgcn_s_barrier()

#define PH_CLOSE_VM2                                             \
    __builtin_amdgcn_s_setprio(0);                               \
    asm volatile("s_waitcnt vmcnt(2)" ::: "memory");             \
    __builtin_amdgcn_s_barrier()

#define PH_CLOSE_VM2_PIN                                         \
    __builtin_amdgcn_sched_barrier(0);                           \
    __builtin_amdgcn_s_setprio(0);                               \
    asm volatile("s_waitcnt vmcnt(2)" ::: "memory");             \
    __builtin_amdgcn_s_barrier()

#define PH_CLOSE_VM0                                             \
    __builtin_amdgcn_s_setprio(0);                               \
    asm volatile("s_waitcnt vmcnt(0)" ::: "memory");             \
    __builtin_amdgcn_s_barrier()

#define STG_A(NB, H)                                                              \
    gl_lds16(pa[H][0], &sm[NB][(H) * 8192 + t * 8]);        pa[H][0] += 64;       \
    gl_lds16(pa[H][1], &sm[NB][(H) * 8192 + 4096 + t * 8]); pa[H][1] += 64;

#define STG_B(NB, H)                                                                      \
    gl_lds16(pb[H][0], &sm[NB][16384 + (H) * 8192 + t * 8]);        pb[H][0] += 64;       \
    gl_lds16(pb[H][1], &sm[NB][16384 + (H) * 8192 + 4096 + t * 8]); pb[H][1] += 64;

#define RD_A(CB, KS)                                                                       \
    _Pragma("unroll") for (int mi = 0; mi < 8; ++mi)                                       \
        afr[mi] = *(const short8*)&sm[CB][(wr * 128 + mi * 16 + l15) * 64 +                \
                                          ((((KS) * 4 + quad) ^ v7) * 8)];

#define RD_B(CB, G, KS)                                                                    \
    (*(const short8*)&sm[CB][16384 + (G) * 4096 + (wc * 16 + l15) * 64 +                   \
                             ((((KS) * 4 + quad) ^ v7) * 8)])

#define MFMA_PAIR(GP)                                                                      \
    _Pragma("unroll") for (int mi = 0; mi < 8; ++mi)                                       \
        acc[mi][2 * (GP)] = __builtin_amdgcn_mfma_f32_16x16x32_bf16(                       \
            afr[mi], b0, acc[mi][2 * (GP)], 0, 0, 0);                                      \
    _Pragma("unroll") for (int mi = 0; mi < 8; ++mi)                                       \
        acc[mi][2 * (GP) + 1] = __builtin_amdgcn_mfma_f32_16x16x32_bf16(                   \
            afr[mi], b1, acc[mi][2 * (GP) + 1], 0, 0, 0);

__global__ __launch_bounds__(512, 2) void lstm_gemm(
    const u16* __restrict__ A, const u16* __restrict__ Wt, const float* __restrict__ c_prev,
    const float* __restrict__ bf_, const float* __restrict__ bi_,
    const float* __restrict__ bg_, const float* __restrict__ bo_,
    float* __restrict__ out) {
    // per buffer: [0,16384) A: m*64 + slot*8 ; [16384,32768) B: g*4096 + n*64 + slot*8
    __shared__ u16 sm[2][32768];   // 128 KiB total

    const int t = threadIdx.x;
    const int w = t >> 6;
    const int l = t & 63;
    const int quad = l >> 4;
    const int l15 = l & 15;
    const int v7 = l15 & 7;
    const int wr = w >> 2;          // 0..1: m-half
    const int wc = w & 3;           // 0..3: 16-col slice
    const int m0 = blockIdx.x * 256;
    const int j0 = blockIdx.y * 64;

    f32x4 acc[8][4];                // [mi][gate]
#pragma unroll
    for (int mi = 0; mi < 8; ++mi)
#pragma unroll
        for (int g = 0; g < 4; ++g)
            acc[mi][g] = (f32x4){0.f, 0.f, 0.f, 0.f};

    // Staging source pointers, pre-swizzled (advance by 64 u16 per K-tile).
    // A half h = m-rows [h*128, h*128+128); B half h = gates {2h, 2h+1}.
    const u16* pa[2][2];
    const u16* pb[2][2];
#pragma unroll
    for (int h = 0; h < 2; ++h)
#pragma unroll
        for (int i = 0; i < 2; ++i) {
            int e = h * 8192 + (i * 512 + t) * 8;
            int m = e >> 6, sl = (e >> 3) & 7;
            pa[h][i] = A + (size_t)(m0 + m) * K_DIM + ((sl ^ (m & 7)) * 8);
            int g = e >> 12, n = (e >> 6) & 63;
            pb[h][i] = Wt + (size_t)g * ((size_t)H_DIM * K_DIM) + (size_t)(j0 + n) * K_DIM +
                       ((sl ^ (n & 7)) * 8);
        }

    short8 afr[8], b0, b1;

    // prologue: stage tile 0 into buf 0 (issue order: A-h0, A-h1, B-g01, B-g23)
    STG_A(0, 0); STG_A(0, 1); STG_B(0, 0); STG_B(0, 1);
    asm volatile("s_waitcnt vmcnt(2)" ::: "memory");   // A + B-g01 landed; B-g23 in flight
    __builtin_amdgcn_s_barrier();

    for (int kt = 0; kt < NTILE - 1; ++kt) {
        const int cb = kt & 1, nb = cb ^ 1;
        // ---- q0: gates 0,1 x ks0 ----
        RD_A(cb, 0);
        b0 = RD_B(cb, 0, 0); b1 = RD_B(cb, 1, 0);
        STG_A(nb, 0);
        PH_OPEN;
        MFMA_PAIR(0);
        PH_CLOSE_VM2;        // B-g23(kt) landed; A-h0(kt+1) in flight
        // ---- q1: gates 2,3 x ks0 ----
        b0 = RD_B(cb, 2, 0); b1 = RD_B(cb, 3, 0);
        STG_A(nb, 1);
        PH_OPEN;
        MFMA_PAIR(1);
        PH_CLOSE;
        // ---- q2: gates 0,1 x ks1 ----
        RD_A(cb, 1);
        b0 = RD_B(cb, 0, 1); b1 = RD_B(cb, 1, 1);
        STG_B(nb, 0);
        PH_OPEN;
        MFMA_PAIR(0);
        PH_CLOSE;
        // ---- q3: gates 2,3 x ks1 ----
        b0 = RD_B(cb, 2, 1); b1 = RD_B(cb, 3, 1);
        STG_B(nb, 1);
        PH_OPEN;
        MFMA_PAIR(1);
        PH_CLOSE_VM2_PIN;    // pinned: MFMAs may not sink past tile boundary
    }
    {   // peeled last tile (cb = 1), no staging
        const int cb = (NTILE - 1) & 1;
        RD_A(cb, 0);
        b0 = RD_B(cb, 0, 0); b1 = RD_B(cb, 1, 0);
        PH_OPEN;
        MFMA_PAIR(0);
        PH_CLOSE_VM0;        // only B-g23(last) outstanding -> full drain
        b0 = RD_B(cb, 2, 0); b1 = RD_B(cb, 3, 0);
        PH_OPEN;
        MFMA_PAIR(1);
        PH_CLOSE;
        RD_A(cb, 1);
        b0 = RD_B(cb, 0, 1); b1 = RD_B(cb, 1, 1);
        PH_OPEN;
        MFMA_PAIR(0);
        PH_CLOSE;
        b0 = RD_B(cb, 2, 1); b1 = RD_B(cb, 3, 1);
        MFMA_PAIR(1);        // compiler auto-waits operands
    }

    // -------- register epilogue: all 4 gates of each output element in one lane --------
    const int col = j0 + wc * 16 + l15;
    const float bF = bf_[col], bI = bi_[col], bG = bg_[col], bO = bo_[col];
#pragma unroll
    for (int mi = 0; mi < 8; ++mi) {
        const int rowbase = m0 + wr * 128 + mi * 16 + quad * 4;   // C/D map: col=lane&15, row=quad*4+reg
        float cp[4];
#pragma unroll
        for (int rr = 0; rr < 4; ++rr)
            cp[rr] = c_prev[(size_t)(rowbase + rr) * H_DIM + col];
#pragma unroll
        for (int rr = 0; rr < 4; ++rr) {
            float fv = sigm(acc[mi][0][rr] + bF);
            float iv = sigm(acc[mi][1][rr] + bI);
            float gv = tanh_f(acc[mi][2][rr] + bG);
            float ov = sigm(acc[mi][3][rr] + bO);
            float cn = fv * cp[rr] + iv * gv;
            float hn = ov * tanh_f(cn);
            size_t idx = (size_t)(rowbase + rr) * H_DIM + col;
            out[idx] = hn;
            out[(size_t)B_DIM * H_DIM + idx] = cn;
        }
    }
}

// ---------- fallback (verified): used only if ws too small ----------
__global__ __launch_bounds__(256) void lstm_f32(
    const float* __restrict__ x, const float* __restrict__ h_prev, const float* __restrict__ c_prev,
    const float* __restrict__ Wf, const float* __restrict__ Wi, const float* __restrict__ Wg, const float* __restrict__ Wo,
    const float* __restrict__ bf_, const float* __restrict__ bi_, const float* __restrict__ bg_, const float* __restrict__ bo_,
    float* __restrict__ out) {
    __shared__ u16 smem[16384];
    u16* sA = smem;
    u16* sB = smem + 4096;

    const int t = threadIdx.x;
    const int w = t >> 6;
    const int l = t & 63;
    const int quad = l >> 4;
    const int l15 = l & 15;
    const int wr = w >> 1;
    const int wc = w & 1;
    const int m0 = blockIdx.x * 128;
    const int j0 = blockIdx.y * 32;

    const int arow = t >> 1;
    const int akh = (t & 1) * 16;
    const int r7 = t & 127;
    const int bk = r7 >> 2;
    const int bn8 = (r7 & 3) * 8;
    const int kswz = ((((bk >> 3) ^ (bn8 >> 3)) << 3) | (bk & 7));
    const float* WpA = (t < 128) ? Wf : Wi;
    const float* WpB = (t < 128) ? Wg : Wo;
    const int gA = (t >> 7);
    const int gB = 2 + (t >> 7);

    f32x4 acc[2][4][2];
#pragma unroll
    for (int gi = 0; gi < 2; ++gi)
#pragma unroll
        for (int mi = 0; mi < 4; ++mi)
#pragma unroll
            for (int ni = 0; ni < 2; ++ni)
                acc[gi][mi][ni] = (f32x4){0.f, 0.f, 0.f, 0.f};

    for (int kt = 0; kt < K_DIM / 32; ++kt) {
        const float* srcA = (kt < 32) ? x : h_prev;
        const int koff = (kt & 31) * 32;
        __syncthreads();

        const float4* ap = (const float4*)(srcA + (size_t)(m0 + arow) * H_DIM + koff + akh);
        float4 a0 = ap[0], a1 = ap[1], a2 = ap[2], a3 = ap[3];
        short8 p0, p1;
        p0[0] = (short)f2bf(a0.x); p0[1] = (short)f2bf(a0.y); p0[2] = (short)f2bf(a0.z); p0[3] = (short)f2bf(a0.w);
        p0[4] = (short)f2bf(a1.x); p0[5] = (short)f2bf(a1.y); p0[6] = (short)f2bf(a1.z); p0[7] = (short)f2bf(a1.w);
        p1[0] = (short)f2bf(a2.x); p1[1] = (short)f2bf(a2.y); p1[2] = (short)f2bf(a2.z); p1[3] = (short)f2bf(a2.w);
        p1[4] = (short)f2bf(a3.x); p1[5] = (short)f2bf(a3.y); p1[6] = (short)f2bf(a3.z); p1[7] = (short)f2bf(a3.w);
        *(short8*)(sA + arow * 32 + akh) = p0;
        *(short8*)(sA + arow * 32 + akh + 8) = p1;

        const float* gpA = WpA + (size_t)(kt * 32 + bk) * H_DIM + j0 + bn8;
        const float* gpB = WpB + (size_t)(kt * 32 + bk) * H_DIM + j0 + bn8;
        float4 c0 = *(const float4*)gpA, c1 = *(const float4*)(gpA + 4);
        float4 d0 = *(const float4*)gpB, d1 = *(const float4*)(gpB + 4);
        sB[gA * 1024 + (bn8 + 0) * 32 + kswz] = f2bf(c0.x);
        sB[gA * 1024 + (bn8 + 1) * 32 + kswz] = f2bf(c0.y);
        sB[gA * 1024 + (bn8 + 2) * 32 + kswz] = f2bf(c0.z);
        sB[gA * 1024 + (bn8 + 3) * 32 + kswz] = f2bf(c0.w);
        sB[gA * 1024 + (bn8 + 4) * 32 + kswz] = f2bf(c1.x);
        sB[gA * 1024 + (bn8 + 5) * 32 + kswz] = f2bf(c1.y);
        sB[gA * 1024 + (bn8 + 6) * 32 + kswz] = f2bf(c1.z);
        sB[gA * 1024 + (bn8 + 7) * 32 + kswz] = f2bf(c1.w);
        sB[gB * 1024 + (bn8 + 0) * 32 + kswz] = f2bf(d0.x);
        sB[gB * 1024 + (bn8 + 1) * 32 + kswz] = f2bf(d0.y);
        sB[gB * 1024 + (bn8 + 2) * 32 + kswz] = f2bf(d0.z);
        sB[gB * 1024 + (bn8 + 3) * 32 + kswz] = f2bf(d0.w);
        sB[gB * 1024 + (bn8 + 4) * 32 + kswz] = f2bf(d1.x);
        sB[gB * 1024 + (bn8 + 5) * 32 + kswz] = f2bf(d1.y);
        sB[gB * 1024 + (bn8 + 6) * 32 + kswz] = f2bf(d1.z);
        sB[gB * 1024 + (bn8 + 7) * 32 + kswz] = f2bf(d1.w);
        __syncthreads();

        short8 bfr[2][2];
#pragma unroll
        for (int gi = 0; gi < 2; ++gi) {
            int g = wc * 2 + gi;
#pragma unroll
            for (int ni = 0; ni < 2; ++ni) {
                int n = ni * 16 + l15;
                bfr[gi][ni] = *(const short8*)(sB + g * 1024 + n * 32 + ((quad ^ (n >> 3)) * 8));
            }
        }
#pragma unroll
        for (int mi = 0; mi < 4; ++mi) {
            int m = wr * 64 + mi * 16 + l15;
            short8 afr = *(const short8*)(sA + m * 32 + quad * 8);
#pragma unroll
            for (int gi = 0; gi < 2; ++gi)
#pragma unroll
                for (int ni = 0; ni < 2; ++ni)
                    acc[gi][mi][ni] =
                        __builtin_amdgcn_mfma_f32_16x16x32_bf16(afr, bfr[gi][ni], acc[gi][mi][ni], 0, 0, 0);
        }
    }

    __syncthreads();
#pragma unroll
    for (int gi = 0; gi < 2; ++gi) {
        int g = wc * 2 + gi;
        const float* bp = (g == 0) ? bf_ : (g == 1) ? bi_ : (g == 2) ? bg_ : bo_;
#pragma unroll
        for (int ni = 0; ni < 2; ++ni) {
            int col = ni * 16 + l15;
            float bias = bp[j0 + col];
#pragma unroll
            for (int mi = 0; mi < 4; ++mi)
#pragma unroll
                for (int rr = 0; rr < 4; ++rr) {
                    int row = wr * 64 + mi * 16 + quad * 4 + rr;
                    float v = acc[gi][mi][ni][rr] + bias;
                    v = (g == 2) ? tanh_f(v) : sigm(v);
                    smem[g * 4096 + row * 32 + col] = f2bf(v);
                }
        }
    }
    __syncthreads();

    const int col = t & 31;
    const int rb = t >> 5;
#pragma unroll
    for (int p = 0; p < 16; ++p) {
        int row = p * 8 + rb;
        float fv = bf2f(smem[0 * 4096 + row * 32 + col]);
        float iv = bf2f(smem[1 * 4096 + row * 32 + col]);
        float gv = bf2f(smem[2 * 4096 + row * 32 + col]);
        float ov = bf2f(smem[3 * 4096 + row * 32 + col]);
        size_t oidx = (size_t)(m0 + row) * H_DIM + j0 + col;
        float cp = c_prev[oidx];
        float cn = fv * cp + iv * gv;
        float hn = ov * tanh_f(cn);
        out[oidx] = hn;
        out[(size_t)B_DIM * H_DIM + oidx] = cn;
    }
}

extern "C" void kernel_launch(void* const* d_in, const int* in_sizes, int n_in,
                              void* d_out, int out_size, void* d_ws, size_t ws_size,
                              hipStream_t stream) {
    const float* x   = (const float*)d_in[0];
    const float* hp  = (const float*)d_in[1];
    const float* cp  = (const float*)d_in[2];
    const float* Wf  = (const float*)d_in[3];
    const float* bf_ = (const float*)d_in[4];
    const float* Wi  = (const float*)d_in[5];
    const float* bi_ = (const float*)d_in[6];
    const float* Wg  = (const float*)d_in[7];
    const float* bg_ = (const float*)d_in[8];
    const float* Wo  = (const float*)d_in[9];
    const float* bo_ = (const float*)d_in[10];

    if (ws_size >= WS_NEEDED) {
        u16* Wt = (u16*)d_ws;
        u16* Ac = (u16*)d_ws + WT_ELEMS;
        prep_all<<<dim3(1024), dim3(256), 0, stream>>>(x, hp, Wf, Wi, Wg, Wo, Ac, Wt);
        lstm_gemm<<<dim3(B_DIM / 256, H_DIM / 64), dim3(512), 0, stream>>>(
            Ac, Wt, cp, bf_, bi_, bg_, bo_, (float*)d_out);
    } else {
        lstm_f32<<<dim3(B_DIM / 128, H_DIM / 32), dim3(256), 0, stream>>>(
            x, hp, cp, Wf, Wi, Wg, Wo, bf_, bi_, bg_, bo_, (float*)d_out);
    }
}